// Round 11
// baseline (33.865 us; speedup 1.0000x reference)
//
#include <hip/hip_runtime.h>
#include <stdint.h>

#define IMG_H 512
#define IMG_W 512
#define NB 16
#define NC 8
#define HW (IMG_H * IMG_W)

#define TH 32                         // tile rows (split for 8 blocks/CU)
#define TW 64                         // tile cols
#define HALO 15
#define CROWS (TH + 2 * HALO)         // 62 dilation rows (rel -15..46)
#define TROWS (TH + 32)               // 64 target patch rows (rel -16..47)
#define TCOLS 96                      // target patch cols (rel -16..79)
#define TSTRIDE 100                   // LDS row stride bytes (25 words, odd)
#define NTASK (CROWS * 3)             // 186 (row,word) tasks -> 1/thread
#define NBLK (NB * 128)               // 2048 blocks = 8 per CU

typedef float f4 __attribute__((ext_vector_type(4)));

// ---------------------------------------------------------------------------
// FULLY FUSED: boundary + capped distance transform + weighted CE per
// 32x64 tile (2048 blocks, 256 threads, __launch_bounds__(256,8) -> 8
// blocks/CU). R10's fixed-point early exit makes the dilation epoch ~free
// (random 8-class targets: level 0 already saturated), so the R8 halo-cost
// objection to the 32-row split no longer applies; the split exists purely
// to double resident waves for the CE stream (MLP/latency-bound at R10's
// 4 blocks/CU).
// ---------------------------------------------------------------------------
__global__ __launch_bounds__(256, 8) void distce_kernel(const float* __restrict__ in,
                                                        const int* __restrict__ tgt,
                                                        float* __restrict__ partials) {
    __shared__ uint8_t  tg[TROWS][TSTRIDE];   // 6400 B
    __shared__ uint32_t cur[2][CROWS][5];     // 2480 B (double buffer, stride 5)
    __shared__ uint8_t  dtile[TH][TW];        // 2048 B
    int b   = blockIdx.x >> 7;
    int tid = blockIdx.x & 127;
    int ty = tid >> 3, tx = tid & 7;
    int ry = ty * TH, rx = tx * TW;
    int t = threadIdx.x;
    const int* tgtb = tgt + (size_t)b * HW;

    if (t < 128) ((uint4*)dtile)[t] = make_uint4(0u, 0u, 0u, 0u);

    // ---- P0: load 64x96 target patch -> LDS bytes ----
    // x-interior tiles (tx 1..6): int4 rows (rx-16 is 16-aligned).
    if (tx >= 1 && tx <= 6) {
        #pragma unroll
        for (int k = 0; k < 6; k++) {
            int tau = t + 256 * k;            // 1536 = 64 rows x 24 int4
            int r = tau / 24, c4 = tau % 24;
            int gy = min(max(ry - 16 + r, 0), IMG_H - 1);
            const int4* rowp = (const int4*)(tgtb + (size_t)gy * IMG_W + rx - 16);
            int4 v = rowp[c4];
            ((uint32_t*)&tg[r][0])[c4] =
                (uint32_t)(v.x & 255) | ((uint32_t)(v.y & 255) << 8) |
                ((uint32_t)(v.z & 255) << 16) | ((uint32_t)(v.w & 255) << 24);
        }
    } else {
        #pragma unroll
        for (int k = 0; k < 24; k++) {
            int tau = t + 256 * k;            // 6144 = 64 x 96 scalars
            int r = tau / TCOLS, c = tau % TCOLS;
            int gy = min(max(ry - 16 + r, 0), IMG_H - 1);
            int gx = min(max(rx - 16 + c, 0), IMG_W - 1);
            tg[r][c] = (uint8_t)tgtb[gy * IMG_W + gx];
        }
    }
    __syncthreads();

    // ---- P1: boundary bit-words (word-parallel XOR trick, verified R6-R10).
    // word w bit i <-> rel col 32w+i-16; clamp-dup == exact; edge bits >=16
    // Chebyshev from the tile are dead within 15 iters. ----
    bool has0 = t < NTASK;
    int r0 = has0 ? (t / 3) : 0, w0 = has0 ? (t % 3) : 0;
    uint32_t o0 = 0u;
    if (has0) {
        int rr = r0 + 1;
        int gy = ry - 15 + r0;
        if (gy >= 0 && gy < IMG_H) {
            uint32_t Wc[10], Wa[10], Wb[10];
            const uint32_t* pc = (const uint32_t*)&tg[rr][0];
            const uint32_t* pa = (const uint32_t*)&tg[rr - 1][0];
            const uint32_t* pb = (const uint32_t*)&tg[rr + 1][0];
            #pragma unroll
            for (int k = 0; k < 10; k++) {
                int idx = 8 * w0 - 1 + k;
                idx = min(max(idx, 0), 23);
                Wc[k] = pc[idx]; Wa[k] = pa[idx]; Wb[k] = pb[idx];
            }
            #pragma unroll
            for (int i = 0; i < 8; i++) {
                uint32_t T = Wc[i + 1];
                uint32_t L = (Wc[i + 1] << 8) | (Wc[i] >> 24);
                uint32_t R = (Wc[i + 1] >> 8) | (Wc[i + 2] << 24);
                uint32_t a = (T ^ L) | (T ^ R);
                uint32_t C2 = Wa[i + 1];
                uint32_t L2 = (Wa[i + 1] << 8) | (Wa[i] >> 24);
                uint32_t R2 = (Wa[i + 1] >> 8) | (Wa[i + 2] << 24);
                a |= (T ^ C2) | (T ^ L2) | (T ^ R2);
                uint32_t C3 = Wb[i + 1];
                uint32_t L3 = (Wb[i + 1] << 8) | (Wb[i] >> 24);
                uint32_t R3 = (Wb[i + 1] >> 8) | (Wb[i + 2] << 24);
                a |= (T ^ C3) | (T ^ L3) | (T ^ R3);
                uint32_t t1  = (a & 0x7F7F7F7Fu) + 0x7F7F7F7Fu;
                uint32_t nzb = ((t1 | a) & 0x80808080u) >> 7;
                o0 |= (((nzb * 0x01020408u) >> 24) & 0xFu) << (4 * i);
            }
            if (tx == 0 && w0 == 0) o0 &= 0xFFFF0000u;   // gx<0 not in image
            if (tx == 7 && w0 == 2) o0 &= 0x0000FFFFu;   // gx>=512 not in image
        }
        cur[0][r0][w0] = o0;
    }
    uint32_t lm0 = (w0 == 0) ? 0xFFFF0000u : (w0 == 1) ? 0xFFFFFFFFu : 0x0000FFFFu;
    bool inner0 = has0 && (r0 >= HALO && r0 < HALO + TH);

    // ---- P2: dilations with fixed-point early exit (exact: saturation is a
    // fixed point; dtile writes are monotone). Vote doubles as the barrier. ----
    int cnt = __syncthreads_count(inner0 && ((o0 | ~lm0) != 0xFFFFFFFFu));
    if (cnt != 0) {
        for (int it = 1; it <= 15; ++it) {
            int pr = (it + 1) & 1, pw = it & 1;
            uint32_t n0 = 0u;
            if (has0) {
                #pragma unroll
                for (int dr = -1; dr <= 1; dr++) {
                    int rr = r0 + dr;
                    if ((unsigned)rr >= (unsigned)CROWS) continue;
                    uint32_t vv = cur[pr][rr][w0];
                    uint32_t lf = (w0 > 0) ? cur[pr][rr][w0 - 1] : 0u;
                    uint32_t rg = (w0 < 2) ? cur[pr][rr][w0 + 1] : 0u;
                    n0 |= vv | (vv << 1) | (vv >> 1) | (lf >> 31) | (rg << 31);
                }
                cur[pw][r0][w0] = n0;
                uint32_t nb = (n0 & ~o0) & lm0;
                o0 = n0;
                if (inner0) {
                    uint32_t x = nb;
                    while (x) { int bit = __ffs(x) - 1; x &= x - 1;
                                dtile[r0 - HALO][w0 * 32 + bit - 16] = (uint8_t)it; }
                }
            }
            cnt = __syncthreads_count(inner0 && ((n0 | ~lm0) != 0xFFFFFFFFu));
            if (cnt == 0) break;
        }
    }

    // ---- P3: CE over the tile (8 px/thread), dist from LDS, reduce ----
    float partial = 0.0f;
    const float* inb = in + (size_t)b * NC * HW;
    #pragma unroll
    for (int g = 0; g < 2; g++) {
        int q = t + 256 * g;
        int row = q >> 4, quad = q & 15;
        const float* base = inb + (size_t)(ry + row) * IMG_W + rx + quad * 4;
        float v[NC][4];
        #pragma unroll
        for (int c = 0; c < NC; c++) {
            f4 f = *(const f4*)(base + (size_t)c * HW);
            v[c][0] = f.x; v[c][1] = f.y; v[c][2] = f.z; v[c][3] = f.w;
        }
        uint32_t tw = ((const uint32_t*)&tg[16 + row][0])[4 + quad];
        uint32_t d4 = *(const uint32_t*)&dtile[row][quad * 4];
        #pragma unroll
        for (int j = 0; j < 4; j++) {
            float mx = v[0][j];
            #pragma unroll
            for (int c = 1; c < NC; c++) mx = fmaxf(mx, v[c][j]);
            float s = 0.0f;
            #pragma unroll
            for (int c = 0; c < NC; c++) s += __expf(v[c][j] - mx);
            float lse = mx + __logf(s);
            int tc = (int)((tw >> (8 * j)) & 0xFFu);
            float lt = v[0][j];
            #pragma unroll
            for (int c = 1; c < NC; c++) lt = (tc == c) ? v[c][j] : lt;
            float ce = lse - lt;
            float d = (float)((d4 >> (8 * j)) & 0xFFu);
            partial += __expf(d * -0.2f) * ce;
        }
    }
    #pragma unroll
    for (int off = 32; off > 0; off >>= 1) partial += __shfl_down(partial, off);
    __shared__ float wsums[4];
    int lane = t & 63;
    int wid = t >> 6;
    if (lane == 0) wsums[wid] = partial;
    __syncthreads();
    if (t == 0)
        partials[blockIdx.x] = wsums[0] + wsums[1] + wsums[2] + wsums[3];
}

// ---------------------------------------------------------------------------
// Deterministic tree-reduce of 2048 partials -> mean. One block.
// ---------------------------------------------------------------------------
__global__ __launch_bounds__(256) void reduce_kernel(const float* __restrict__ partials,
                                                     float* __restrict__ out) {
    double s = 0.0;
    #pragma unroll
    for (int i = 0; i < NBLK / 256; i++)
        s += (double)partials[threadIdx.x + 256 * i];
    #pragma unroll
    for (int off = 32; off > 0; off >>= 1) s += __shfl_down(s, off);
    __shared__ double wsums[4];
    int lane = threadIdx.x & 63;
    int wid = threadIdx.x >> 6;
    if (lane == 0) wsums[wid] = s;
    __syncthreads();
    if (threadIdx.x == 0) {
        double tot = wsums[0] + wsums[1] + wsums[2] + wsums[3];
        out[0] = (float)(tot * (1.0 / (double)((size_t)NB * HW)));
    }
}

extern "C" void kernel_launch(void* const* d_in, const int* in_sizes, int n_in,
                              void* d_out, int out_size, void* d_ws, size_t ws_size,
                              hipStream_t stream) {
    const float* in  = (const float*)d_in[0];
    const int*   tgt = (const int*)d_in[1];
    float* out = (float*)d_out;

    float* partials = (float*)((char*)d_ws + 256);   // 8 KB

    distce_kernel<<<NBLK, 256, 0, stream>>>(in, tgt, partials);
    reduce_kernel<<<1, 256, 0, stream>>>(partials, out);
}

// Round 12
// 33.453 us; speedup vs baseline: 1.0123x; 1.0123x over previous
//
#include <hip/hip_runtime.h>
#include <stdint.h>

#define IMG_H 512
#define IMG_W 512
#define NB 16
#define NC 8
#define HW (IMG_H * IMG_W)

#define TILE 64
#define HALO 15
#define CROWS 94                      // dilation rows (rel -15..78)
#define TROWS 96                      // target patch rows (rel -16..79)
#define TCOLS 96                      // target patch cols (rel -16..79)
#define TSTRIDE 100                   // LDS row stride bytes (25 words, odd)
#define NTASK (CROWS * 3)             // 282 (row,word) tasks
#define NBLK (NB * 64)                // 1024 blocks (16 img x 8x8 tiles)

typedef float f4 __attribute__((ext_vector_type(4)));

// ---------------------------------------------------------------------------
// FULLY FUSED: boundary + capped distance transform + weighted CE per 64x64
// tile (R10 structure, best-known 32.07 us) + FIRST-GROUP PREFETCH: the 8
// plane loads of quad-group 0 are issued at kernel entry, before the patch
// staging / boundary words / saturation vote, so the logits stream starts at
// dispatch instead of after ~2us of front-matter. The __syncthreads fences
// keep the loads pinned at the top. +32 VGPR (36 -> ~75), still >=4
// waves/SIMD at this grid's 4 blocks/CU.
// ---------------------------------------------------------------------------
__global__ __launch_bounds__(256) void distce_kernel(const float* __restrict__ in,
                                                     const int* __restrict__ tgt,
                                                     float* __restrict__ partials) {
    __shared__ uint8_t  tg[TROWS][TSTRIDE];   // 9600 B
    __shared__ uint32_t cur[2][CROWS][5];     // 3760 B (double buffer, stride 5)
    __shared__ uint8_t  dtile[TILE][TILE];    // 4096 B
    int b   = blockIdx.x >> 6;
    int tid = blockIdx.x & 63;
    int ty = tid >> 3, tx = tid & 7;
    int ry = ty * TILE, rx = tx * TILE;
    int t = threadIdx.x;
    const int* tgtb = tgt + (size_t)b * HW;
    const float* inb = in + (size_t)b * NC * HW;

    // ---- prefetch quad-group 0 (8 planes) -> registers ----
    int prow = t >> 4, pquad = t & 15;
    const float* pbase = inb + (size_t)(ry + prow) * IMG_W + rx + pquad * 4;
    f4 pre[NC];
    #pragma unroll
    for (int c = 0; c < NC; c++) pre[c] = *(const f4*)(pbase + (size_t)c * HW);

    ((uint4*)dtile)[t] = make_uint4(0u, 0u, 0u, 0u);

    // ---- P0: load 96x96 target patch -> LDS bytes ----
    if (tx >= 1 && tx <= 6) {
        #pragma unroll
        for (int k = 0; k < 9; k++) {
            int tau = t + 256 * k;            // 2304 = 96 rows x 24 int4
            int r = tau / 24, c4 = tau % 24;
            int gy = min(max(ry - 16 + r, 0), IMG_H - 1);
            const int4* rowp = (const int4*)(tgtb + (size_t)gy * IMG_W + rx - 16);
            int4 v = rowp[c4];
            ((uint32_t*)&tg[r][0])[c4] =
                (uint32_t)(v.x & 255) | ((uint32_t)(v.y & 255) << 8) |
                ((uint32_t)(v.z & 255) << 16) | ((uint32_t)(v.w & 255) << 24);
        }
    } else {
        #pragma unroll
        for (int k = 0; k < 36; k++) {
            int tau = t + 256 * k;
            int r = tau / TCOLS, c = tau % TCOLS;
            int gy = min(max(ry - 16 + r, 0), IMG_H - 1);
            int gx = min(max(rx - 16 + c, 0), IMG_W - 1);
            tg[r][c] = (uint8_t)tgtb[gy * IMG_W + gx];
        }
    }
    __syncthreads();

    // ---- P1: boundary bit-words (word-parallel XOR trick, verified R6-R11) ----
    auto bword = [&](int r, int w) -> uint32_t {
        int rr = r + 1;
        int gy = ry - 15 + r;
        uint32_t word = 0u;
        if (gy >= 0 && gy < IMG_H) {
            uint32_t Wc[10], Wa[10], Wb[10];
            const uint32_t* pc = (const uint32_t*)&tg[rr][0];
            const uint32_t* pa = (const uint32_t*)&tg[rr - 1][0];
            const uint32_t* pb = (const uint32_t*)&tg[rr + 1][0];
            #pragma unroll
            for (int k = 0; k < 10; k++) {
                int idx = 8 * w - 1 + k;
                idx = min(max(idx, 0), 23);
                Wc[k] = pc[idx]; Wa[k] = pa[idx]; Wb[k] = pb[idx];
            }
            #pragma unroll
            for (int i = 0; i < 8; i++) {
                uint32_t T = Wc[i + 1];
                uint32_t L = (Wc[i + 1] << 8) | (Wc[i] >> 24);
                uint32_t R = (Wc[i + 1] >> 8) | (Wc[i + 2] << 24);
                uint32_t a = (T ^ L) | (T ^ R);
                uint32_t C2 = Wa[i + 1];
                uint32_t L2 = (Wa[i + 1] << 8) | (Wa[i] >> 24);
                uint32_t R2 = (Wa[i + 1] >> 8) | (Wa[i + 2] << 24);
                a |= (T ^ C2) | (T ^ L2) | (T ^ R2);
                uint32_t C3 = Wb[i + 1];
                uint32_t L3 = (Wb[i + 1] << 8) | (Wb[i] >> 24);
                uint32_t R3 = (Wb[i + 1] >> 8) | (Wb[i + 2] << 24);
                a |= (T ^ C3) | (T ^ L3) | (T ^ R3);
                uint32_t t1  = (a & 0x7F7F7F7Fu) + 0x7F7F7F7Fu;
                uint32_t nzb = ((t1 | a) & 0x80808080u) >> 7;
                word |= (((nzb * 0x01020408u) >> 24) & 0xFu) << (4 * i);
            }
            if (tx == 0 && w == 0) word &= 0xFFFF0000u;   // gx<0 not in image
            if (tx == 7 && w == 2) word &= 0x0000FFFFu;   // gx>=512 not in image
        }
        return word;
    };
    int r0 = t / 3, w0 = t % 3;
    uint32_t o0 = bword(r0, w0);
    cur[0][r0][w0] = o0;
    bool has1 = (t + 256) < NTASK;
    int r1 = (t + 256) / 3, w1 = (t + 256) % 3;
    if (has1) cur[0][r1][w1] = bword(r1, w1);   // rows 85..93: never inner
    uint32_t lm0 = (w0 == 0) ? 0xFFFF0000u : (w0 == 1) ? 0xFFFFFFFFu : 0x0000FFFFu;
    bool inner0 = (r0 >= HALO && r0 < HALO + TILE);

    // ---- P2: dilations with fixed-point early exit (exact: saturation is a
    // fixed point; dtile writes monotone). Vote doubles as the barrier. ----
    int cnt = __syncthreads_count(inner0 && ((o0 | ~lm0) != 0xFFFFFFFFu));
    if (cnt != 0) {
        for (int it = 1; it <= 15; ++it) {
            int pr = (it + 1) & 1, pw = it & 1;
            uint32_t n0 = 0u;
            #pragma unroll
            for (int dr = -1; dr <= 1; dr++) {
                int rr = r0 + dr;
                if ((unsigned)rr >= (unsigned)CROWS) continue;
                uint32_t vv = cur[pr][rr][w0];
                uint32_t lf = (w0 > 0) ? cur[pr][rr][w0 - 1] : 0u;
                uint32_t rg = (w0 < 2) ? cur[pr][rr][w0 + 1] : 0u;
                n0 |= vv | (vv << 1) | (vv >> 1) | (lf >> 31) | (rg << 31);
            }
            cur[pw][r0][w0] = n0;
            uint32_t nb = (n0 & ~o0) & lm0;
            o0 = n0;
            if (inner0) {
                uint32_t x = nb;
                while (x) { int bit = __ffs(x) - 1; x &= x - 1;
                            dtile[r0 - HALO][w0 * 32 + bit - 16] = (uint8_t)it; }
            }
            if (has1) {
                uint32_t n1 = 0u;
                #pragma unroll
                for (int dr = -1; dr <= 1; dr++) {
                    int rr = r1 + dr;
                    if ((unsigned)rr >= (unsigned)CROWS) continue;
                    uint32_t vv = cur[pr][rr][w1];
                    uint32_t lf = (w1 > 0) ? cur[pr][rr][w1 - 1] : 0u;
                    uint32_t rg = (w1 < 2) ? cur[pr][rr][w1 + 1] : 0u;
                    n1 |= vv | (vv << 1) | (vv >> 1) | (lf >> 31) | (rg << 31);
                }
                cur[pw][r1][w1] = n1;
            }
            cnt = __syncthreads_count(inner0 && ((n0 | ~lm0) != 0xFFFFFFFFu));
            if (cnt == 0) break;
        }
    }

    // ---- P3: CE over the tile (16 px/thread), dist from LDS, reduce ----
    float partial = 0.0f;
    #pragma unroll
    for (int g = 0; g < 4; g++) {
        int q = t + 256 * g;
        int row = q >> 4, quad = q & 15;
        const float* base = inb + (size_t)(ry + row) * IMG_W + rx + quad * 4;
        float v[NC][4];
        #pragma unroll
        for (int c = 0; c < NC; c++) {
            f4 f = (g == 0) ? pre[c] : *(const f4*)(base + (size_t)c * HW);
            v[c][0] = f.x; v[c][1] = f.y; v[c][2] = f.z; v[c][3] = f.w;
        }
        uint32_t tw = ((const uint32_t*)&tg[16 + row][0])[4 + quad];
        uint32_t d4 = *(const uint32_t*)&dtile[row][quad * 4];
        #pragma unroll
        for (int j = 0; j < 4; j++) {
            float mx = v[0][j];
            #pragma unroll
            for (int c = 1; c < NC; c++) mx = fmaxf(mx, v[c][j]);
            float s = 0.0f;
            #pragma unroll
            for (int c = 0; c < NC; c++) s += __expf(v[c][j] - mx);
            float lse = mx + __logf(s);
            int tc = (int)((tw >> (8 * j)) & 0xFFu);
            float lt = v[0][j];
            #pragma unroll
            for (int c = 1; c < NC; c++) lt = (tc == c) ? v[c][j] : lt;
            float ce = lse - lt;
            float d = (float)((d4 >> (8 * j)) & 0xFFu);
            partial += __expf(d * -0.2f) * ce;
        }
    }
    #pragma unroll
    for (int off = 32; off > 0; off >>= 1) partial += __shfl_down(partial, off);
    __shared__ float wsums[4];
    int lane = t & 63;
    int wid = t >> 6;
    if (lane == 0) wsums[wid] = partial;
    __syncthreads();
    if (t == 0)
        partials[blockIdx.x] = wsums[0] + wsums[1] + wsums[2] + wsums[3];
}

// ---------------------------------------------------------------------------
// Deterministic tree-reduce of 1024 partials -> mean. One block.
// ---------------------------------------------------------------------------
__global__ __launch_bounds__(256) void reduce_kernel(const float* __restrict__ partials,
                                                     float* __restrict__ out) {
    double s = 0.0;
    #pragma unroll
    for (int i = 0; i < NBLK / 256; i++)
        s += (double)partials[threadIdx.x + 256 * i];
    #pragma unroll
    for (int off = 32; off > 0; off >>= 1) s += __shfl_down(s, off);
    __shared__ double wsums[4];
    int lane = threadIdx.x & 63;
    int wid = threadIdx.x >> 6;
    if (lane == 0) wsums[wid] = s;
    __syncthreads();
    if (threadIdx.x == 0) {
        double tot = wsums[0] + wsums[1] + wsums[2] + wsums[3];
        out[0] = (float)(tot * (1.0 / (double)((size_t)NB * HW)));
    }
}

extern "C" void kernel_launch(void* const* d_in, const int* in_sizes, int n_in,
                              void* d_out, int out_size, void* d_ws, size_t ws_size,
                              hipStream_t stream) {
    const float* in  = (const float*)d_in[0];
    const int*   tgt = (const int*)d_in[1];
    float* out = (float*)d_out;

    float* partials = (float*)((char*)d_ws + 256);   // 4 KB

    distce_kernel<<<NBLK, 256, 0, stream>>>(in, tgt, partials);
    reduce_kernel<<<1, 256, 0, stream>>>(partials, out);
}

// Round 15
// 32.341 us; speedup vs baseline: 1.0471x; 1.0344x over previous
//
#include <hip/hip_runtime.h>
#include <stdint.h>

#define IMG_H 512
#define IMG_W 512
#define NB 16
#define NC 8
#define HW (IMG_H * IMG_W)

#define TILE 64
#define HALO 15
#define CROWS 94                      // dilation rows (rel -15..78)
#define TROWS 96                      // target patch rows (rel -16..79)
#define TCOLS 96                      // target patch cols (rel -16..79)
#define TSTRIDE 100                   // LDS row stride bytes (25 words, odd)
#define NTASK (CROWS * 3)             // 282 (row,word) tasks
#define NBLK (NB * 64)                // 1024 blocks (16 img x 8x8 tiles)

typedef float f4 __attribute__((ext_vector_type(4)));

// ---------------------------------------------------------------------------
// R10 REVERT (best-known: 32.07 us, absmax 0.0). FULLY FUSED boundary +
// capped distance transform + weighted CE per 64x64 tile; separate 1-block
// reduce kernel (the dispatch boundary is the XCD coherence fence — R13/R14
// proved in-kernel cross-block reduction is unsafe on 8 non-coherent XCDs).
// ---------------------------------------------------------------------------
__global__ __launch_bounds__(256) void distce_kernel(const float* __restrict__ in,
                                                     const int* __restrict__ tgt,
                                                     float* __restrict__ partials) {
    __shared__ uint8_t  tg[TROWS][TSTRIDE];   // 9600 B
    __shared__ uint32_t cur[2][CROWS][5];     // 3760 B (double buffer, stride 5)
    __shared__ uint8_t  dtile[TILE][TILE];    // 4096 B
    int b   = blockIdx.x >> 6;
    int tid = blockIdx.x & 63;
    int ty = tid >> 3, tx = tid & 7;
    int ry = ty * TILE, rx = tx * TILE;
    int t = threadIdx.x;
    const int* tgtb = tgt + (size_t)b * HW;
    const float* inb = in + (size_t)b * NC * HW;

    ((uint4*)dtile)[t] = make_uint4(0u, 0u, 0u, 0u);

    // ---- P0: load 96x96 target patch -> LDS bytes ----
    if (tx >= 1 && tx <= 6) {
        #pragma unroll
        for (int k = 0; k < 9; k++) {
            int tau = t + 256 * k;            // 2304 = 96 rows x 24 int4
            int r = tau / 24, c4 = tau % 24;
            int gy = min(max(ry - 16 + r, 0), IMG_H - 1);
            const int4* rowp = (const int4*)(tgtb + (size_t)gy * IMG_W + rx - 16);
            int4 v = rowp[c4];
            ((uint32_t*)&tg[r][0])[c4] =
                (uint32_t)(v.x & 255) | ((uint32_t)(v.y & 255) << 8) |
                ((uint32_t)(v.z & 255) << 16) | ((uint32_t)(v.w & 255) << 24);
        }
    } else {
        #pragma unroll
        for (int k = 0; k < 36; k++) {
            int tau = t + 256 * k;
            int r = tau / TCOLS, c = tau % TCOLS;
            int gy = min(max(ry - 16 + r, 0), IMG_H - 1);
            int gx = min(max(rx - 16 + c, 0), IMG_W - 1);
            tg[r][c] = (uint8_t)tgtb[gy * IMG_W + gx];
        }
    }
    __syncthreads();

    // ---- P1: boundary bit-words (word-parallel XOR trick, verified R6-R12) ----
    auto bword = [&](int r, int w) -> uint32_t {
        int rr = r + 1;
        int gy = ry - 15 + r;
        uint32_t word = 0u;
        if (gy >= 0 && gy < IMG_H) {
            uint32_t Wc[10], Wa[10], Wb[10];
            const uint32_t* pc = (const uint32_t*)&tg[rr][0];
            const uint32_t* pa = (const uint32_t*)&tg[rr - 1][0];
            const uint32_t* pb = (const uint32_t*)&tg[rr + 1][0];
            #pragma unroll
            for (int k = 0; k < 10; k++) {
                int idx = 8 * w - 1 + k;
                idx = min(max(idx, 0), 23);
                Wc[k] = pc[idx]; Wa[k] = pa[idx]; Wb[k] = pb[idx];
            }
            #pragma unroll
            for (int i = 0; i < 8; i++) {
                uint32_t T = Wc[i + 1];
                uint32_t L = (Wc[i + 1] << 8) | (Wc[i] >> 24);
                uint32_t R = (Wc[i + 1] >> 8) | (Wc[i + 2] << 24);
                uint32_t a = (T ^ L) | (T ^ R);
                uint32_t C2 = Wa[i + 1];
                uint32_t L2 = (Wa[i + 1] << 8) | (Wa[i] >> 24);
                uint32_t R2 = (Wa[i + 1] >> 8) | (Wa[i + 2] << 24);
                a |= (T ^ C2) | (T ^ L2) | (T ^ R2);
                uint32_t C3 = Wb[i + 1];
                uint32_t L3 = (Wb[i + 1] << 8) | (Wb[i] >> 24);
                uint32_t R3 = (Wb[i + 1] >> 8) | (Wb[i + 2] << 24);
                a |= (T ^ C3) | (T ^ L3) | (T ^ R3);
                uint32_t t1  = (a & 0x7F7F7F7Fu) + 0x7F7F7F7Fu;
                uint32_t nzb = ((t1 | a) & 0x80808080u) >> 7;
                word |= (((nzb * 0x01020408u) >> 24) & 0xFu) << (4 * i);
            }
            if (tx == 0 && w == 0) word &= 0xFFFF0000u;   // gx<0 not in image
            if (tx == 7 && w == 2) word &= 0x0000FFFFu;   // gx>=512 not in image
        }
        return word;
    };
    int r0 = t / 3, w0 = t % 3;
    uint32_t o0 = bword(r0, w0);
    cur[0][r0][w0] = o0;
    bool has1 = (t + 256) < NTASK;
    int r1 = (t + 256) / 3, w1 = (t + 256) % 3;
    if (has1) cur[0][r1][w1] = bword(r1, w1);   // rows 85..93: never inner
    uint32_t lm0 = (w0 == 0) ? 0xFFFF0000u : (w0 == 1) ? 0xFFFFFFFFu : 0x0000FFFFu;
    bool inner0 = (r0 >= HALO && r0 < HALO + TILE);

    // ---- P2: dilations with fixed-point early exit (exact: saturation is a
    // fixed point; dtile writes monotone). Vote doubles as the barrier. ----
    int cnt = __syncthreads_count(inner0 && ((o0 | ~lm0) != 0xFFFFFFFFu));
    if (cnt != 0) {
        for (int it = 1; it <= 15; ++it) {
            int pr = (it + 1) & 1, pw = it & 1;
            uint32_t n0 = 0u;
            #pragma unroll
            for (int dr = -1; dr <= 1; dr++) {
                int rr = r0 + dr;
                if ((unsigned)rr >= (unsigned)CROWS) continue;
                uint32_t vv = cur[pr][rr][w0];
                uint32_t lf = (w0 > 0) ? cur[pr][rr][w0 - 1] : 0u;
                uint32_t rg = (w0 < 2) ? cur[pr][rr][w0 + 1] : 0u;
                n0 |= vv | (vv << 1) | (vv >> 1) | (lf >> 31) | (rg << 31);
            }
            cur[pw][r0][w0] = n0;
            uint32_t nb = (n0 & ~o0) & lm0;
            o0 = n0;
            if (inner0) {
                uint32_t x = nb;
                while (x) { int bit = __ffs(x) - 1; x &= x - 1;
                            dtile[r0 - HALO][w0 * 32 + bit - 16] = (uint8_t)it; }
            }
            if (has1) {
                uint32_t n1 = 0u;
                #pragma unroll
                for (int dr = -1; dr <= 1; dr++) {
                    int rr = r1 + dr;
                    if ((unsigned)rr >= (unsigned)CROWS) continue;
                    uint32_t vv = cur[pr][rr][w1];
                    uint32_t lf = (w1 > 0) ? cur[pr][rr][w1 - 1] : 0u;
                    uint32_t rg = (w1 < 2) ? cur[pr][rr][w1 + 1] : 0u;
                    n1 |= vv | (vv << 1) | (vv >> 1) | (lf >> 31) | (rg << 31);
                }
                cur[pw][r1][w1] = n1;
            }
            cnt = __syncthreads_count(inner0 && ((n0 | ~lm0) != 0xFFFFFFFFu));
            if (cnt == 0) break;
        }
    }

    // ---- P3: CE over the tile (16 px/thread), dist from LDS, reduce ----
    float partial = 0.0f;
    #pragma unroll
    for (int g = 0; g < 4; g++) {
        int q = t + 256 * g;
        int row = q >> 4, quad = q & 15;
        const float* base = inb + (size_t)(ry + row) * IMG_W + rx + quad * 4;
        float v[NC][4];
        #pragma unroll
        for (int c = 0; c < NC; c++) {
            f4 f = *(const f4*)(base + (size_t)c * HW);
            v[c][0] = f.x; v[c][1] = f.y; v[c][2] = f.z; v[c][3] = f.w;
        }
        uint32_t tw = ((const uint32_t*)&tg[16 + row][0])[4 + quad];
        uint32_t d4 = *(const uint32_t*)&dtile[row][quad * 4];
        #pragma unroll
        for (int j = 0; j < 4; j++) {
            float mx = v[0][j];
            #pragma unroll
            for (int c = 1; c < NC; c++) mx = fmaxf(mx, v[c][j]);
            float s = 0.0f;
            #pragma unroll
            for (int c = 0; c < NC; c++) s += __expf(v[c][j] - mx);
            float lse = mx + __logf(s);
            int tc = (int)((tw >> (8 * j)) & 0xFFu);
            float lt = v[0][j];
            #pragma unroll
            for (int c = 1; c < NC; c++) lt = (tc == c) ? v[c][j] : lt;
            float ce = lse - lt;
            float d = (float)((d4 >> (8 * j)) & 0xFFu);
            partial += __expf(d * -0.2f) * ce;
        }
    }
    #pragma unroll
    for (int off = 32; off > 0; off >>= 1) partial += __shfl_down(partial, off);
    __shared__ float wsums[4];
    int lane = t & 63;
    int wid = t >> 6;
    if (lane == 0) wsums[wid] = partial;
    __syncthreads();
    if (t == 0)
        partials[blockIdx.x] = wsums[0] + wsums[1] + wsums[2] + wsums[3];
}

// ---------------------------------------------------------------------------
// Deterministic tree-reduce of 1024 partials -> mean. One block.
// ---------------------------------------------------------------------------
__global__ __launch_bounds__(256) void reduce_kernel(const float* __restrict__ partials,
                                                     float* __restrict__ out) {
    double s = 0.0;
    #pragma unroll
    for (int i = 0; i < NBLK / 256; i++)
        s += (double)partials[threadIdx.x + 256 * i];
    #pragma unroll
    for (int off = 32; off > 0; off >>= 1) s += __shfl_down(s, off);
    __shared__ double wsums[4];
    int lane = threadIdx.x & 63;
    int wid = threadIdx.x >> 6;
    if (lane == 0) wsums[wid] = s;
    __syncthreads();
    if (threadIdx.x == 0) {
        double tot = wsums[0] + wsums[1] + wsums[2] + wsums[3];
        out[0] = (float)(tot * (1.0 / (double)((size_t)NB * HW)));
    }
}

extern "C" void kernel_launch(void* const* d_in, const int* in_sizes, int n_in,
                              void* d_out, int out_size, void* d_ws, size_t ws_size,
                              hipStream_t stream) {
    const float* in  = (const float*)d_in[0];
    const int*   tgt = (const int*)d_in[1];
    float* out = (float*)d_out;

    float* partials = (float*)((char*)d_ws + 256);   // 4 KB

    distce_kernel<<<NBLK, 256, 0, stream>>>(in, tgt, partials);
    reduce_kernel<<<1, 256, 0, stream>>>(partials, out);
}